// Round 3
// baseline (25.761 us; speedup 1.0000x reference)
//
#include <hip/hip_runtime.h>
#include <math.h>

// DETR HungarianMatcher cost matrix on MI355X — round 3.
// C[n,m] = 5*L1 - prob[n,label[m]] - 2*GIoU, [16000 x 1024] f32 out.
// Block = 256 threads, ROWS=16 rows/block. Each thread owns 4 CONSECUTIVE
// targets (m = 4t+k) -> one float4 store per row. LDS holds (2 - prob) and
// packed per-row pred-box vectors (2x float4 + area). Row loop fully
// unrolled so LDS broadcast reads use immediate offsets.

#define NROWS 16000
#define NC 92
#define M_TGT 1024
#define TPB 256
#define ROWS 16
#define KPT 4   // consecutive targets per thread (KPT*TPB == M_TGT)

__global__ __launch_bounds__(TPB) void hungarian_cost_kernel(
    const float* __restrict__ logits,   // [NROWS, NC]
    const float* __restrict__ pboxes,   // [NROWS, 4] cxcywh
    const float* __restrict__ tboxes,   // [M_TGT, 4] cxcywh
    const int*   __restrict__ tlabels,  // [M_TGT]
    float* __restrict__ out)            // [NROWS, M_TGT]
{
    const int n0 = blockIdx.x * ROWS;
    const int t = threadIdx.x;
    const int lane = t & 63;
    const int wid  = t >> 6;

    __shared__ float negp[ROWS][NC];   // 2 - softmax prob
    __shared__ float rowv[ROWS][12];   // [pcx pcy pw ph][ax0 ay0 ax1 ay1][area_a ...]

    // ---- per-thread target context (registers), m = 4t + k ----
    float tcx[KPT], tcy[KPT], twd[KPT], tht[KPT];
    float bx0[KPT], by0[KPT], bx1[KPT], by1[KPT], areab[KPT];
    const int4 lb4 = reinterpret_cast<const int4*>(tlabels)[t];
    int lbl[KPT] = {lb4.x, lb4.y, lb4.z, lb4.w};
    #pragma unroll
    for (int k = 0; k < KPT; ++k) {
        const float4 tb = reinterpret_cast<const float4*>(tboxes)[4 * t + k];
        tcx[k] = tb.x; tcy[k] = tb.y; twd[k] = tb.z; tht[k] = tb.w;
        bx0[k] = tb.x - 0.5f * tb.z;  by0[k] = tb.y - 0.5f * tb.w;
        bx1[k] = tb.x + 0.5f * tb.z;  by1[k] = tb.y + 0.5f * tb.w;
        areab[k] = tb.z * tb.w;
        lbl[k] = (lbl[k] < 0) ? 0 : (lbl[k] > NC - 1 ? NC - 1 : lbl[k]);
    }

    // ---- softmax: wave `wid` handles rows 4*wid .. 4*wid+3 ----
    #pragma unroll
    for (int j = 0; j < 4; ++j) {
        const int r = wid * 4 + j;
        const float* lg = logits + (size_t)(n0 + r) * NC;
        const float x0 = lg[lane];                 // lane < 64 < NC
        const bool  hi = (lane < NC - 64);         // lanes 0..27 cover 64..91
        const float x1 = hi ? lg[64 + lane] : -INFINITY;
        float mx = fmaxf(x0, x1);
        #pragma unroll
        for (int off = 32; off >= 1; off >>= 1)
            mx = fmaxf(mx, __shfl_xor(mx, off));
        const float e0 = __expf(x0 - mx);
        const float e1 = hi ? __expf(x1 - mx) : 0.0f;
        float s = e0 + e1;
        #pragma unroll
        for (int off = 32; off >= 1; off >>= 1)
            s += __shfl_xor(s, off);
        const float rs = __builtin_amdgcn_rcpf(s);
        negp[r][lane] = fmaf(-e0, rs, 2.0f);
        if (hi) negp[r][64 + lane] = fmaf(-e1, rs, 2.0f);
    }

    // ---- per-row pred-box vectors ----
    if (t < ROWS) {
        const float4 pb = reinterpret_cast<const float4*>(pboxes)[n0 + t];
        rowv[t][0] = pb.x; rowv[t][1] = pb.y; rowv[t][2] = pb.z; rowv[t][3] = pb.w;
        rowv[t][4] = pb.x - 0.5f * pb.z;  rowv[t][5] = pb.y - 0.5f * pb.w;
        rowv[t][6] = pb.x + 0.5f * pb.z;  rowv[t][7] = pb.y + 0.5f * pb.w;
        rowv[t][8] = pb.z * pb.w;         // area_a
    }
    __syncthreads();

    // ---- main: 16 rows, 4 consecutive targets/thread, float4 stores ----
    float* obase = out + (size_t)n0 * M_TGT + 4 * t;
    #pragma unroll
    for (int r = 0; r < ROWS; ++r) {
        const float4 pc = *reinterpret_cast<const float4*>(&rowv[r][0]); // cx cy w h
        const float4 pe = *reinterpret_cast<const float4*>(&rowv[r][4]); // x0 y0 x1 y1
        const float area_a = rowv[r][8];
        float tmp[KPT];
        #pragma unroll
        for (int k = 0; k < KPT; ++k) {
            const float cls2 = negp[r][lbl[k]];   // 2 - prob[target class]
            const float cb = fabsf(pc.x - tcx[k]) + fabsf(pc.y - tcy[k])
                           + fabsf(pc.z - twd[k]) + fabsf(pc.w - tht[k]);
            const float iwu = fminf(pe.z, bx1[k]) - fmaxf(pe.x, bx0[k]);
            const float ihu = fminf(pe.w, by1[k]) - fmaxf(pe.y, by0[k]);
            const float inter = fmaxf(iwu, 0.0f) * fmaxf(ihu, 0.0f);
            const float uni = area_a + areab[k] - inter;
            const float ew = pc.z + twd[k] - iwu;   // max(a1,b1)-min(a0,b0)
            const float eh = pc.w + tht[k] - ihu;
            const float ae = ew * eh;
            // cost = 5*cb + (2 - cls) - 2*iou - 2*uni/ae
            tmp[k] = fmaf(5.0f, cb, cls2)
                   - 2.0f * inter * __builtin_amdgcn_rcpf(uni)
                   - 2.0f * uni   * __builtin_amdgcn_rcpf(ae);
        }
        float4 res = {tmp[0], tmp[1], tmp[2], tmp[3]};
        *reinterpret_cast<float4*>(obase + (size_t)r * M_TGT) = res;
    }
}

extern "C" void kernel_launch(void* const* d_in, const int* in_sizes, int n_in,
                              void* d_out, int out_size, void* d_ws, size_t ws_size,
                              hipStream_t stream) {
    const float* logits  = (const float*)d_in[0];  // [16,1000,92]
    const float* pboxes  = (const float*)d_in[1];  // [16,1000,4]
    const float* tboxes  = (const float*)d_in[2];  // [1024,4]
    const int*   tlabels = (const int*)d_in[3];    // [1024]
    float* out = (float*)d_out;                    // [16,1000,1024]

    hungarian_cost_kernel<<<NROWS / ROWS, TPB, 0, stream>>>(
        logits, pboxes, tboxes, tlabels, out);
}